// Round 2
// baseline (41.752 us; speedup 1.0000x reference)
//
#include <hip/hip_runtime.h>

// SegmentationLoss: scalar = sum_{b,l,i} g[b,l,i] * sqrt(sum_f (p[b,l,f]-g[b,l,i])^2)
// Shapes: input (8,16,256,256) f32, target (8,8,256,256) f32, out: 1 f32.
// Identity: sum_f (p_f - g)^2 = s2 - 2 g s1 + NF g^2  with s1=sum p_f, s2=sum p_f^2.
//
// Occupancy fix: 4-way split of per-location work. Each thread owns 4 channels
// (partial s1/s2) and 2 instances; lanes {q,q+16,q+32,q+48} share the same 16
// float4-location groups and combine s1/s2 via shfl_xor(16|32). 8192 waves total
// = 8 waves/SIMD (vs 2 before).

#define HW   (256 * 256)
#define NF   16
#define NI   8
#define BSZ  8

__global__ __launch_bounds__(256) void seg_loss_kernel(const float* __restrict__ input,
                                                       const float* __restrict__ target,
                                                       float* __restrict__ out) {
    const int tid   = blockIdx.x * blockDim.x + threadIdx.x;   // 0 .. 524287
    const int lane  = threadIdx.x & 63;
    const int sub   = lane >> 4;            // 0..3: channel/instance subgroup
    const int qlane = lane & 15;
    const int wave  = tid >> 6;             // global wave id 0..8191
    const int group = (wave << 4) + qlane;  // float4-group id 0..131071

    const int b = group >> 14;              // (group*4) / 65536
    const int l = (group & 16383) << 2;     // location offset within image

    const float4* ip = reinterpret_cast<const float4*>(
        input + (size_t)b * NF * HW + (size_t)(sub * 4) * HW + l);
    const float4* tp = reinterpret_cast<const float4*>(
        target + (size_t)b * NI * HW + (size_t)(sub * 2) * HW + l);

    float4 s1 = make_float4(0.f, 0.f, 0.f, 0.f);
    float4 s2 = make_float4(0.f, 0.f, 0.f, 0.f);
#pragma unroll
    for (int k = 0; k < 4; ++k) {
        float4 p = ip[k * (HW / 4)];
        s1.x += p.x; s1.y += p.y; s1.z += p.z; s1.w += p.w;
        s2.x += p.x * p.x; s2.y += p.y * p.y; s2.z += p.z * p.z; s2.w += p.w * p.w;
    }

    // Combine partial s1/s2 across the 4 channel subgroups (lanes xor 16, 32).
#pragma unroll
    for (int m = 16; m <= 32; m <<= 1) {
        s1.x += __shfl_xor(s1.x, m, 64);
        s1.y += __shfl_xor(s1.y, m, 64);
        s1.z += __shfl_xor(s1.z, m, 64);
        s1.w += __shfl_xor(s1.w, m, 64);
        s2.x += __shfl_xor(s2.x, m, 64);
        s2.y += __shfl_xor(s2.y, m, 64);
        s2.z += __shfl_xor(s2.z, m, 64);
        s2.w += __shfl_xor(s2.w, m, 64);
    }

    float acc = 0.f;
#pragma unroll
    for (int j = 0; j < 2; ++j) {
        float4 g = tp[j * (HW / 4)];
        acc += g.x * sqrtf(fmaxf(s2.x - 2.f * g.x * s1.x + (float)NF * g.x * g.x, 0.f));
        acc += g.y * sqrtf(fmaxf(s2.y - 2.f * g.y * s1.y + (float)NF * g.y * g.y, 0.f));
        acc += g.z * sqrtf(fmaxf(s2.z - 2.f * g.z * s1.z + (float)NF * g.z * g.z, 0.f));
        acc += g.w * sqrtf(fmaxf(s2.w - 2.f * g.w * s1.w + (float)NF * g.w * g.w, 0.f));
    }

    // Full-wave (64-lane) reduction
#pragma unroll
    for (int off = 32; off > 0; off >>= 1)
        acc += __shfl_down(acc, off, 64);

    __shared__ float wsum[4];
    const int wid = threadIdx.x >> 6;
    if (lane == 0) wsum[wid] = acc;
    __syncthreads();
    if (threadIdx.x == 0) {
        float s = wsum[0] + wsum[1] + wsum[2] + wsum[3];
        atomicAdd(out, s);
    }
}

extern "C" void kernel_launch(void* const* d_in, const int* in_sizes, int n_in,
                              void* d_out, int out_size, void* d_ws, size_t ws_size,
                              hipStream_t stream) {
    const float* input  = (const float*)d_in[0];
    const float* target = (const float*)d_in[1];
    float* out = (float*)d_out;

    hipMemsetAsync(out, 0, sizeof(float), stream);

    const int total_threads = BSZ * HW;       // 524288 (4 threads per float4-group)
    const int block = 256;
    const int grid  = total_threads / block;  // 2048
    seg_loss_kernel<<<grid, block, 0, stream>>>(input, target, out);
}

// Round 3
// 15.707 us; speedup vs baseline: 2.6582x; 2.6582x over previous
//
#include <hip/hip_runtime.h>

// SegmentationLoss: scalar = sum_{b,l,i} g[b,l,i] * sqrt(sum_f (p[b,l,f]-g[b,l,i])^2)
// input (8,16,256,256) f32, target (8,8,256,256) f32, out: 1 f32.
// Identity: sum_f (p_f - g)^2 = s2 - 2 g s1 + NF g^2,  s1=sum_f p_f, s2=sum_f p_f^2.
//
// Round-3 structure: NO ATOMICS (round 1/2 were dominated by a same-line
// device-atomic serialization tail). Two kernels:
//   stage1: 2048 blocks x 256 thr. Block owns 64 float4-groups (256 locations).
//           Wave w loads channels 4w..4w+3 (1KB-contiguous per instruction),
//           partial s1/s2 combined across waves via LDS; wave w then handles
//           instances 2w,2w+1. One partial float per block -> d_ws.
//   stage2: one block reduces the 2048 partials into out[0].

#define HW      (256 * 256)
#define NF      16
#define NI      8
#define BSZ     8
#define NGROUPS (BSZ * HW / 4)     // 131072 float4-groups
#define GPB     64                 // groups per block
#define NBLK    (NGROUPS / GPB)    // 2048

__global__ __launch_bounds__(256, 8) void seg_loss_stage1(const float* __restrict__ input,
                                                          const float* __restrict__ target,
                                                          float* __restrict__ partial) {
    const int lane = threadIdx.x & 63;
    const int wid  = threadIdx.x >> 6;
    const int base = blockIdx.x * GPB;                      // group base (multiple of 64)
    const int b    = base >> 14;                            // 16384 groups per batch image
    const int loc  = ((base & 16383) << 2) + (lane << 2);   // element offset within image

    const float* ibase = input  + (size_t)b * NF * HW + loc;
    const float* tbase = target + (size_t)b * NI * HW + loc;

    // Phase 1: wave `wid` accumulates partial s1/s2 over channels 4*wid..4*wid+3.
    float4 s1 = make_float4(0.f, 0.f, 0.f, 0.f);
    float4 s2 = make_float4(0.f, 0.f, 0.f, 0.f);
#pragma unroll
    for (int k = 0; k < 4; ++k) {
        float4 p = *reinterpret_cast<const float4*>(ibase + (size_t)(4 * wid + k) * HW);
        s1.x += p.x; s1.y += p.y; s1.z += p.z; s1.w += p.w;
        s2.x += p.x * p.x; s2.y += p.y * p.y; s2.z += p.z * p.z; s2.w += p.w * p.w;
    }

    __shared__ float4 sm1[4][64];
    __shared__ float4 sm2[4][64];
    sm1[wid][lane] = s1;
    sm2[wid][lane] = s2;
    __syncthreads();

    // Combine the 4 channel-partials for this lane's 4 locations.
    float4 t1 = make_float4(0.f, 0.f, 0.f, 0.f);
    float4 t2 = make_float4(0.f, 0.f, 0.f, 0.f);
#pragma unroll
    for (int w = 0; w < 4; ++w) {
        float4 a = sm1[w][lane];
        float4 c = sm2[w][lane];
        t1.x += a.x; t1.y += a.y; t1.z += a.z; t1.w += a.w;
        t2.x += c.x; t2.y += c.y; t2.z += c.z; t2.w += c.w;
    }

    // Phase 2: wave `wid` handles instances 2*wid and 2*wid+1.
    float acc = 0.f;
#pragma unroll
    for (int j = 0; j < 2; ++j) {
        float4 g = *reinterpret_cast<const float4*>(tbase + (size_t)(2 * wid + j) * HW);
        acc += g.x * sqrtf(fmaxf(t2.x - 2.f * g.x * t1.x + (float)NF * g.x * g.x, 0.f));
        acc += g.y * sqrtf(fmaxf(t2.y - 2.f * g.y * t1.y + (float)NF * g.y * g.y, 0.f));
        acc += g.z * sqrtf(fmaxf(t2.z - 2.f * g.z * t1.z + (float)NF * g.z * g.z, 0.f));
        acc += g.w * sqrtf(fmaxf(t2.w - 2.f * g.w * t1.w + (float)NF * g.w * g.w, 0.f));
    }

    // Wave reduction, then block reduction via LDS. No atomics.
#pragma unroll
    for (int off = 32; off > 0; off >>= 1)
        acc += __shfl_down(acc, off, 64);

    __shared__ float wsum[4];
    if (lane == 0) wsum[wid] = acc;
    __syncthreads();
    if (threadIdx.x == 0)
        partial[blockIdx.x] = wsum[0] + wsum[1] + wsum[2] + wsum[3];
}

__global__ __launch_bounds__(256) void seg_loss_stage2(const float* __restrict__ partial,
                                                       float* __restrict__ out) {
    float s = 0.f;
#pragma unroll
    for (int k = 0; k < NBLK / 256; ++k)
        s += partial[k * 256 + threadIdx.x];

#pragma unroll
    for (int off = 32; off > 0; off >>= 1)
        s += __shfl_down(s, off, 64);

    __shared__ float wsum[4];
    const int lane = threadIdx.x & 63;
    const int wid  = threadIdx.x >> 6;
    if (lane == 0) wsum[wid] = s;
    __syncthreads();
    if (threadIdx.x == 0)
        out[0] = wsum[0] + wsum[1] + wsum[2] + wsum[3];
}

extern "C" void kernel_launch(void* const* d_in, const int* in_sizes, int n_in,
                              void* d_out, int out_size, void* d_ws, size_t ws_size,
                              hipStream_t stream) {
    const float* input  = (const float*)d_in[0];
    const float* target = (const float*)d_in[1];
    float* out     = (float*)d_out;
    float* partial = (float*)d_ws;   // 2048 floats = 8 KB of scratch

    seg_loss_stage1<<<NBLK, 256, 0, stream>>>(input, target, partial);
    seg_loss_stage2<<<1, 256, 0, stream>>>(partial, out);
}